// Round 17
// baseline (1386.477 us; speedup 1.0000x reference)
//
#include <hip/hip_runtime.h>
#include <math.h>

#define NB 16
#define SEQ 1024
#define DM 512
#define KD 128
#define TEMP_F 30.0f
#define NS_F 0.011048543456039805f   // sqrt(1/8192)
#define DS_F 524288.0f               // D*H*W = 512*1024

// SS: per-stage slabs; 32 batch slots; one cache line per counter
#define SS_IDX(grp, b) (((grp) * 32 + (b)) * 16)
#define SS_STRIDE 1536
#define SS_STAGES 12
#define SS_FLOATS (SS_STRIDE * SS_STAGES)

// P scratch row stride (us): 144B rows, 16B-aligned b128 reads.
#define PSTR 72

typedef short bf16x8 __attribute__((ext_vector_type(8)));
typedef float f32x4 __attribute__((ext_vector_type(4)));
typedef unsigned short us;
typedef unsigned short us4v __attribute__((ext_vector_type(4)));
typedef unsigned short us8 __attribute__((ext_vector_type(8)));

__device__ __forceinline__ us f2bf(float x) {
    union { float f; unsigned u; } v; v.f = x;
    unsigned r = v.u + 0x7fffu + ((v.u >> 16) & 1u);
    return (us)(r >> 16);
}
__device__ __forceinline__ float bf2f(us h) {
    union { unsigned u; float f; } v; v.u = ((unsigned)h) << 16;
    return v.f;
}

// global -> LDS async 16B/lane. lds dst = wave-uniform base + lane*16 implicit.
#define GLL16(gp, lp) __builtin_amdgcn_global_load_lds( \
    (__attribute__((address_space(1))) void*)(unsigned long long)(gp), \
    (__attribute__((address_space(3))) void*)(unsigned)(unsigned long long)(lp), 16, 0, 0)

// ---------------- transpose in: src [16][D][S] f32 -> XC [.][S][1024] bf16 hi|lo + XT [.][D][S] bf16 ----------------
__global__ __launch_bounds__(256) void k_transpose_in(const float* __restrict__ src,
                                                      us* __restrict__ XC,
                                                      us* __restrict__ XT) {
    __shared__ float tile[32][33];
    const int b = blockIdx.z;
    const int d0 = blockIdx.x * 32;
    const int s0 = blockIdx.y * 32;
    const int tx = threadIdx.x, ty = threadIdx.y;  // 32x8
    const float* p = src + (size_t)b * DM * SEQ;
    us* pt = XT + (size_t)b * DM * SEQ;
    us* pc = XC + (size_t)b * SEQ * 1024;
#pragma unroll
    for (int j = 0; j < 32; j += 8) {
        const size_t o = (size_t)(d0 + ty + j) * SEQ + s0 + tx;
        const float v = p[o];
        tile[ty + j][tx] = v;
        pt[o] = f2bf(v);
    }
    __syncthreads();
#pragma unroll
    for (int j = 0; j < 4; ++j) {
        const int s = s0 + ty + j * 8;
        const int d = d0 + tx;
        const float v = tile[tx][ty + j * 8];
        const us h = f2bf(v);
        pc[(size_t)s * 1024 + d] = h;
        pc[(size_t)s * 1024 + 512 + d] = f2bf(v - bf2f(h));
    }
}

// ---------------- MEMLT[b][d][s] = MEMT[b][d][s] * label[b][s] ----------------
__global__ __launch_bounds__(256) void k_mklabel(const us* __restrict__ MT,
                                                 const float* __restrict__ label,
                                                 us* __restrict__ ML) {
    const int b = blockIdx.y;
    const size_t off = ((size_t)blockIdx.x * 256 + threadIdx.x) * 8;
    const int s = (int)(off & (SEQ - 1));
    const size_t o = (size_t)b * DM * SEQ + off;
    us8 v = *(const us8*)(MT + o);
    const float4 l0 = *(const float4*)(label + (size_t)b * SEQ + s);
    const float4 l1 = *(const float4*)(label + (size_t)b * SEQ + s + 4);
    us8 r;
    r[0] = f2bf(bf2f(v[0]) * l0.x); r[1] = f2bf(bf2f(v[1]) * l0.y);
    r[2] = f2bf(bf2f(v[2]) * l0.z); r[3] = f2bf(bf2f(v[3]) * l0.w);
    r[4] = f2bf(bf2f(v[4]) * l1.x); r[5] = f2bf(bf2f(v[5]) * l1.y);
    r[6] = f2bf(bf2f(v[6]) * l1.z); r[7] = f2bf(bf2f(v[7]) * l1.w);
    *(us8*)(ML + o) = r;
}

// ---------------- weight split: WK [DM][KD] f32 -> WC [KD][1024] bf16 hi|lo ----------------
__global__ __launch_bounds__(256) void k_wsplit(const float* __restrict__ WK,
                                                us* __restrict__ WC) {
    const int k = blockIdx.x;  // 0..KD
    for (int d = threadIdx.x; d < DM; d += 256) {
        const float v = WK[(size_t)d * KD + k];
        const us h = f2bf(v);
        WC[(size_t)k * 1024 + d] = h;
        WC[(size_t)k * 1024 + 512 + d] = f2bf(v - bf2f(h));
    }
}

// ---------------- projection GEMM: Wout[row][0:128]=hi,[128:256]=lo of l2norm(X@WK+bK) ----------------
__global__ __launch_bounds__(256) void k_proj(const us* __restrict__ XC,
                                              const us* __restrict__ WC,
                                              const float* __restrict__ bK,
                                              us* __restrict__ Wout) {
    const int row0 = blockIdx.x * 32;
    __shared__ short As[32 * 64], Bs[128 * 64];
    __shared__ float ssp[2][32];
    const int tid = threadIdx.x, w = tid >> 6, l = tid & 63;
    const int wm = (w >> 1) * 16, wn = (w & 1) * 64;
    const int sr = l >> 3, sc = (((l & 7) ^ (l >> 3)) << 3);
    const int lr = l & 15, lk = (l >> 4) * 8;
    const int sx = (lr & 7) << 3;
    f32x4 acc[4] = {};
    for (int k0 = 0; k0 < 1536; k0 += 64) {
        const int ak0 = (k0 < 1024) ? k0 : k0 - 1024;
        const int bk0 = (k0 < 512) ? k0 : k0 - 512;
        GLL16(XC + (size_t)(row0 + w * 8 + sr) * 1024 + ak0 + sc, &As[w * 512]);
#pragma unroll
        for (int cc = 0; cc < 4; ++cc) {
            const int c = 4 * w + cc;
            GLL16(WC + (size_t)(c * 8 + sr) * 1024 + bk0 + sc, &Bs[c * 512]);
        }
        __syncthreads();
#pragma unroll
        for (int kc = 0; kc < 2; ++kc) {
            const int kk = kc * 32 + lk;
            const bf16x8 a = *(const bf16x8*)&As[(wm + lr) * 64 + (kk ^ sx)];
            bf16x8 bb[4];
#pragma unroll
            for (int fn = 0; fn < 4; ++fn)
                bb[fn] = *(const bf16x8*)&Bs[(wn + fn * 16 + lr) * 64 + (kk ^ sx)];
#pragma unroll
            for (int fn = 0; fn < 4; ++fn)
                acc[fn] = __builtin_amdgcn_mfma_f32_16x16x32_bf16(a, bb[fn], acc[fn], 0, 0, 0);
        }
        __syncthreads();
    }
    const int er = l & 15, eq = (l >> 4) * 4;
    const int nh = w & 1;
    float bkv[4];
#pragma unroll
    for (int fn = 0; fn < 4; ++fn) bkv[fn] = bK[wn + fn * 16 + er];
    float vv[4][4];
#pragma unroll
    for (int r = 0; r < 4; ++r) {
        float ss = 0.f;
#pragma unroll
        for (int fn = 0; fn < 4; ++fn) {
            const float t = acc[fn][r] + bkv[fn];
            vv[fn][r] = t;
            ss += t * t;
        }
#pragma unroll
        for (int o = 8; o > 0; o >>= 1) ss += __shfl_xor(ss, o, 64);
        if (er == 0) ssp[nh][wm + eq + r] = ss;
    }
    __syncthreads();
#pragma unroll
    for (int r = 0; r < 4; ++r) {
        const int rowloc = wm + eq + r;
        const float tot = ssp[0][rowloc] + ssp[1][rowloc];
        const float invn = 1.0f / fmaxf(sqrtf(tot), 1e-12f);
        const size_t ro = (size_t)(row0 + rowloc) * 256;
#pragma unroll
        for (int fn = 0; fn < 4; ++fn) {
            const float ov = vv[fn][r] * invn;
            const us h = f2bf(ov);
            Wout[ro + wn + fn * 16 + er] = h;
            Wout[ro + 128 + wn + fn * 16 + er] = f2bf(ov - bf2f(h));
        }
    }
}

// ---------------- flash attention v9: 8 waves, q64, s64, swapped QK; K AND V stream
// global->VGPR (L2-resident per batch); only P goes through LDS (dbuf, 1 barrier/iter). ----------------
__global__ __launch_bounds__(512, 2) void k_attn(const us* __restrict__ Qc,
                                                 const us* __restrict__ Kc,
                                                 const us* __restrict__ VT,
                                                 const us* __restrict__ XC,
                                                 const float* __restrict__ labelp,
                                                 float* __restrict__ MVEC,
                                                 float* __restrict__ Cout,
                                                 float* __restrict__ SS, int mode, int kvmask) {
    const int b = blockIdx.x;
    const int bkv = b & kvmask;
    const int q0 = blockIdx.y * 64;
    __shared__ us PL[2][64 * PSTR];          // 2x9 KB: P [64 q][64 s + pad]
    __shared__ float RSL[2][64], RLL[2][64];
    __shared__ float INVL[64], MVL[64];
    __shared__ float ps[3][8];
    const int tid = threadIdx.x, w = tid >> 6, l = tid & 63;
    const int lr = l & 15, g = l >> 4, lk = g * 8;
    const int qa = w & 3, sh = w >> 2;
    const us* Qb = Qc + (size_t)b * SEQ * 256;
    const us* Kb = Kc + (size_t)bkv * SEQ * 256;
    const us* Vb = VT + (size_t)bkv * DM * SEQ;
    const float* Lb = labelp ? labelp + (size_t)(bkv & 15) * SEQ : nullptr;

    // ---- Q fragments in registers (hi + lo) for this wave's 16 q (lane lr <-> q col) ----
    const us* Qrow = Qb + (size_t)(q0 + qa * 16 + lr) * 256;
    bf16x8 qh[4], ql[4];
#pragma unroll
    for (int kc = 0; kc < 4; ++kc) {
        qh[kc] = *(const bf16x8*)(Qrow + kc * 32 + lk);
        ql[kc] = *(const bf16x8*)(Qrow + 128 + kc * 32 + lk);
    }

    f32x4 acc[4][4];
#pragma unroll
    for (int m = 0; m < 4; ++m)
#pragma unroll
        for (int n = 0; n < 4; ++n) acc[m][n] = (f32x4){0.f, 0.f, 0.f, 0.f};
    float rs = 0.f, rl = 0.f;
    for (int it = 0; it < 16; ++it) {
        const int s0 = it * 64;
        const int pb = it & 1;
        // ---- V fragments ks=0: direct global (hide under QK) ----
        bf16x8 vb0[4];
#pragma unroll
        for (int n = 0; n < 4; ++n)
            vb0[n] = *(const bf16x8*)(Vb + (size_t)(w * 64 + n * 16 + lr) * 1024 + s0 + lk);
        // ---- QK swapped: two 16q x 16s sub-tiles (sn); K fragments direct global ----
#pragma unroll
        for (int sn = 0; sn < 2; ++sn) {
            const int srow = sh * 32 + sn * 16 + lr;
            const us* Krow = Kb + (size_t)(s0 + srow) * 256;
            f32x4 sacc = {};
            bf16x8 kf[4];
#pragma unroll
            for (int kc = 0; kc < 4; ++kc)
                kf[kc] = *(const bf16x8*)(Krow + kc * 32 + lk);          // K hi
            __builtin_amdgcn_s_setprio(1);
#pragma unroll
            for (int kc = 0; kc < 4; ++kc)
                sacc = __builtin_amdgcn_mfma_f32_16x16x32_bf16(kf[kc], qh[kc], sacc, 0, 0, 0);
#pragma unroll
            for (int kc = 0; kc < 4; ++kc)
                sacc = __builtin_amdgcn_mfma_f32_16x16x32_bf16(kf[kc], ql[kc], sacc, 0, 0, 0);
            __builtin_amdgcn_s_setprio(0);
#pragma unroll
            for (int kc = 0; kc < 4; ++kc)
                kf[kc] = *(const bf16x8*)(Krow + 128 + kc * 32 + lk);    // K lo
            __builtin_amdgcn_s_setprio(1);
#pragma unroll
            for (int kc = 0; kc < 4; ++kc)
                sacc = __builtin_amdgcn_mfma_f32_16x16x32_bf16(kf[kc], qh[kc], sacc, 0, 0, 0);
            __builtin_amdgcn_s_setprio(0);
            // exp + scalar rowsum partials + packed P write (lane: q=lr, s=sh*32+sn*16+g*4+r)
            const int sbase = sh * 32 + sn * 16 + g * 4;
            float lb4[4] = {0.f, 0.f, 0.f, 0.f};
            if (mode == 2) {
                const float4 t = *(const float4*)(Lb + s0 + sbase);
                lb4[0] = t.x; lb4[1] = t.y; lb4[2] = t.z; lb4[3] = t.w;
            }
            us4v pw;
#pragma unroll
            for (int r = 0; r < 4; ++r) {
                const float e = __expf(fmaf(TEMP_F, sacc[r], -TEMP_F));
                rs += e;
                rl += e * lb4[r];
                pw[r] = f2bf(e);
            }
            *(us4v*)&PL[pb][(qa * 16 + lr) * PSTR + sbase] = pw;
        }
        __syncthreads();   // P(it) visible to all waves
        // ---- V fragments ks=1 (hidden under PV ks=0) ----
        bf16x8 vb1[4];
#pragma unroll
        for (int n = 0; n < 4; ++n)
            vb1[n] = *(const bf16x8*)(Vb + (size_t)(w * 64 + n * 16 + lr) * 1024 + s0 + 32 + lk);
        // ---- PV d-split: wave covers all 64 q x its 64-d slice; two ks steps ----
        const us* PLc = PL[pb];
        bf16x8 pa[4];
#pragma unroll
        for (int m = 0; m < 4; ++m)
            pa[m] = *(const bf16x8*)&PLc[(m * 16 + lr) * PSTR + lk];
        __builtin_amdgcn_s_setprio(1);
#pragma unroll
        for (int m = 0; m < 4; ++m)
#pragma unroll
            for (int n = 0; n < 4; ++n)
                acc[m][n] = __builtin_amdgcn_mfma_f32_16x16x32_bf16(pa[m], vb0[n], acc[m][n], 0, 0, 0);
        __builtin_amdgcn_s_setprio(0);
#pragma unroll
        for (int m = 0; m < 4; ++m)
            pa[m] = *(const bf16x8*)&PLc[(m * 16 + lr) * PSTR + 32 + lk];
        __builtin_amdgcn_s_setprio(1);
#pragma unroll
        for (int m = 0; m < 4; ++m)
#pragma unroll
            for (int n = 0; n < 4; ++n)
                acc[m][n] = __builtin_amdgcn_mfma_f32_16x16x32_bf16(pa[m], vb1[n], acc[m][n], 0, 0, 0);
        __builtin_amdgcn_s_setprio(0);
        // no end-of-iter barrier: next iter writes PL[pb^1]; PL[pb] is next rewritten
        // by QK(it+2), which is after barrier(it+1).
    }

    // ---- rowsum combine: cross-g shfl, then cross s-half via LDS ----
    rs += __shfl_xor(rs, 16, 64);
    rs += __shfl_xor(rs, 32, 64);
    rl += __shfl_xor(rl, 16, 64);
    rl += __shfl_xor(rl, 32, 64);
    __syncthreads();
    if (g == 0) {
        RSL[sh][qa * 16 + lr] = rs;
        RLL[sh][qa * 16 + lr] = rl;
    }
    __syncthreads();
    if (tid < 64) {
        const float tot = RSL[0][tid] + RSL[1][tid];
        const float iv = 1.0f / tot;
        INVL[tid] = iv;
        const float mvv = (RLL[0][tid] + RLL[1][tid]) * iv;
        MVL[tid] = mvv;
        if (mode == 2) MVEC[(size_t)b * SEQ + q0 + tid] = mvv;
    }
    __syncthreads();

    // ---- epilogue: normalize, residual, SS ----
    const us* XCb = XC + (size_t)b * SEQ * 1024;
    float sa = 0.f, sb = 0.f, sab = 0.f;
#pragma unroll
    for (int m = 0; m < 4; ++m)
#pragma unroll
        for (int r = 0; r < 4; ++r) {
            const int q = m * 16 + g * 4 + r;
            const float iv = INVL[q];
            const float mvq = MVL[q];
            const int row = q0 + q;
#pragma unroll
            for (int n = 0; n < 4; ++n) {
                const int col = w * 64 + n * 16 + lr;
                float v = acc[m][n][r] * iv;
                const size_t o = ((size_t)b * SEQ + row) * DM + col;
                const size_t xo = (size_t)row * 1024 + col;
                const float x = bf2f(XCb[xo]) + bf2f(XCb[xo + 512]);
                v += x;
                sb += v * v;
                if (mode == 2) { const float a = x * mvq; sa += a * a; sab += a * v; }
                Cout[o] = v;
            }
        }
#pragma unroll
    for (int off = 32; off > 0; off >>= 1) {
        sb += __shfl_xor(sb, off, 64);
        if (mode == 2) { sa += __shfl_xor(sa, off, 64); sab += __shfl_xor(sab, off, 64); }
    }
    if (l == 0) { ps[0][w] = sb; ps[1][w] = sa; ps[2][w] = sab; }
    __syncthreads();
    if (tid == 0) {
        float t0 = 0.f, t1 = 0.f, t2 = 0.f;
#pragma unroll
        for (int i = 0; i < 8; ++i) { t0 += ps[0][i]; t1 += ps[1][i]; t2 += ps[2][i]; }
        if (mode == 1) {
            atomicAdd(&SS[SS_IDX(0, b)], t0);
        } else {
            atomicAdd(&SS[SS_IDX(0, b)], t1);
            atomicAdd(&SS[SS_IDX(1, b)], t0);
            atomicAdd(&SS[SS_IDX(2, b)], t2);
        }
    }
}

// ---------------- zero all SS stages ----------------
__global__ void k_zero(float* __restrict__ SSb) {
    const int i = blockIdx.x * 256 + threadIdx.x;
    if (i < SS_FLOATS) SSb[i] = 0.0f;
}

// ---------------- finish: v from T (+XC), write XC hi|lo + transposed bf16/f32 ----------------
// mode 0: v = f3*T ; mode 1: v = f3*(f1*x*mv + f2*T)  (T holds x+t3)
__global__ __launch_bounds__(256) void k_finish(const float* __restrict__ Tin,
                                                const us* __restrict__ XCin,
                                                const float* __restrict__ mv,
                                                const float* __restrict__ SS,
                                                us* __restrict__ XCout,
                                                us* __restrict__ XTb,
                                                float* __restrict__ XTf,
                                                int mode, int writeXC) {
    const int b = blockIdx.z;
    const int s0 = blockIdx.x * 32, d0 = blockIdx.y * 32;
    const int tx = threadIdx.x, ty = threadIdx.y;
    __shared__ float tile[32][33];
    float f1 = 0.f, f2 = 0.f, f3;
    if (mode == 0) {
        f3 = NS_F * sqrtf(DS_F / (SS[SS_IDX(0, b)] + 1e-5f));
    } else {
        const float ssa = SS[SS_IDX(0, b)], ssb = SS[SS_IDX(1, b)], ssab = SS[SS_IDX(2, b)];
        f1 = NS_F * sqrtf(DS_F / (ssa + 1e-5f));
        f2 = NS_F * sqrtf(DS_F / (ssb + 1e-5f));
        const float ssc = f1 * f1 * ssa + 2.f * f1 * f2 * ssab + f2 * f2 * ssb;
        f3 = NS_F * sqrtf(DS_F / (ssc + 1e-5f));
    }
#pragma unroll
    for (int j = 0; j < 4; ++j) {
        const int s = s0 + ty + j * 8;
        const int d = d0 + tx;
        const size_t o = ((size_t)b * SEQ + s) * DM + d;
        const size_t xo = ((size_t)b * SEQ + s) * 1024 + d;
        float v;
        if (mode == 0) v = f3 * Tin[o];
        else {
            const float x = bf2f(XCin[xo]) + bf2f(XCin[xo + 512]);
            v = f3 * (f1 * x * mv[(size_t)b * SEQ + s] + f2 * Tin[o]);
        }
        if (writeXC) {
            const us h = f2bf(v);
            XCout[xo] = h;
            XCout[xo + 512] = f2bf(v - bf2f(h));
        }
        tile[ty + j * 8][tx] = v;
    }
    __syncthreads();
#pragma unroll
    for (int j = 0; j < 4; ++j) {
        const int d = d0 + ty + j * 8;
        const int s = s0 + tx;
        const float v = tile[tx][ty + j * 8];
        const size_t o = ((size_t)b * DM + d) * SEQ + s;
        if (XTb) XTb[o] = f2bf(v);
        else if (XTf) XTf[o] = v;
    }
}

extern "C" void kernel_launch(void* const* d_in, const int* in_sizes, int n_in,
                              void* d_out, int out_size, void* d_ws, size_t ws_size,
                              hipStream_t stream) {
    const float* train_feat = (const float*)d_in[0];
    const float* test_feat  = (const float*)d_in[1];
    const float* label      = (const float*)d_in[2];
    const float* WKs        = (const float*)d_in[3];
    const float* bKs        = (const float*)d_in[4];
    const float* WKc        = (const float*)d_in[5];
    const float* bKc        = (const float*)d_in[6];
    float* out = (float*)d_out;
    float* w = (float*)d_ws;

    const size_t PB  = (size_t)SEQ * DM;        // 524,288 elems per batch
    const size_t SBD = (size_t)NB * PB;         // 16-batch slab

    // choose merged (32-batch stream) if workspace allows
    auto needF = [&](size_t nbat) {
        return nbat * (PB /*T*/ + PB /*XC(us2)*/ + PB / 2 /*XTd*/ + PB / 4 /*W1C*/ + 1024 /*MVEC*/)
             + (size_t)NB * (PB / 2 /*MEMT*/ + PB / 2 /*MEMLT*/ + PB / 4 /*WKMC*/)
             + 2 * (size_t)KD * 512 /*WCs+WCc*/ + SS_FLOATS + 4096;
    };
    const size_t wsf = ws_size / 4;
    const int nbat = (wsf >= needF(32)) ? 32 : NB;

    float* T    = w;                                   // nbat*PB f32
    us* XC      = (us*)(T + (size_t)nbat * PB);        // nbat*2*PB us (hi|lo)
    us* XTd     = XC + (size_t)nbat * 2 * PB;          // nbat*PB us
    us* W1C     = XTd + (size_t)nbat * PB;             // nbat*PB/2 us
    us* MEMT    = W1C + (size_t)nbat * PB / 2;         // NB*PB us
    us* MEMLT   = MEMT + (size_t)NB * PB;              // NB*PB us
    us* WKMC    = MEMLT + (size_t)NB * PB;             // NB*PB/2 us
    us* WCs     = WKMC + (size_t)NB * PB / 2;          // KD*1024 us
    us* WCc     = WCs + (size_t)KD * 1024;
    float* MVEC = (float*)(WCc + (size_t)KD * 1024);   // nbat*SEQ f32
    float* SS   = MVEC + (size_t)nbat * SEQ;           // SS_FLOATS

    const dim3 gT_in(DM / 32, SEQ / 32, NB), bT(32, 8);

    int stage = 0;
    auto nextSS = [&]() { return SS + (size_t)(stage++) * SS_STRIDE; };

    // ---------------- setup ----------------
    k_zero<<<(SS_FLOATS + 255) / 256, 256, 0, stream>>>(SS);
    k_wsplit<<<KD, 256, 0, stream>>>(WKs, WCs);
    k_wsplit<<<KD, 256, 0, stream>>>(WKc, WCc);

    // ---------------- encoder (16 batches, in first 16 slots) ----------------
    k_transpose_in<<<gT_in, bT, 0, stream>>>(train_feat, XC, MEMT);
    for (int l = 0; l < 2; ++l) {
        float* SSst = nextSS();
        k_proj<<<NB * SEQ / 32, 256, 0, stream>>>(XC, WCs, bKs, W1C);
        k_attn<<<dim3(NB, SEQ / 64), 512, 0, stream>>>(W1C, W1C, MEMT, XC, nullptr, nullptr, T, SSst, 1, 63);
        k_finish<<<dim3(SEQ / 32, DM / 32, NB), bT, 0, stream>>>(T, XC, nullptr, SSst, XC, MEMT, nullptr, 0, 1);
    }
    k_proj<<<NB * SEQ / 32, 256, 0, stream>>>(XC, WCc, bKc, WKMC);
    k_mklabel<<<dim3(DM * SEQ / 8 / 256, NB), 256, 0, stream>>>(MEMT, label, MEMLT);

    // ---------------- decoder stages over `db` batches starting at slot 0 ----------------
    auto dec_layers = [&](int db, float* outp) {
        const dim3 gA(db, SEQ / 64);
        const dim3 gF(SEQ / 32, DM / 32, db);
        for (int l = 0; l < 2; ++l) {
            // self-attn + inorm
            float* SSst = nextSS();
            k_proj<<<db * SEQ / 32, 256, 0, stream>>>(XC, WCs, bKs, W1C);
            k_attn<<<gA, 512, 0, stream>>>(W1C, W1C, XTd, XC, nullptr, nullptr, T, SSst, 1, 63);
            k_finish<<<gF, bT, 0, stream>>>(T, XC, nullptr, SSst, XC, XTd, nullptr, 0, 1);
            // cross-attn (fused reduce3): T = x + t3; SS = ssa/ssb/ssab; MVEC = mask
            float* SSst2 = nextSS();
            k_proj<<<db * SEQ / 32, 256, 0, stream>>>(XC, WCc, bKc, W1C);
            k_attn<<<gA, 512, 0, stream>>>(W1C, WKMC, MEMLT, XC, label, MVEC, T, SSst2, 2, 15);
            // fused triple instance-norm finish
            if (l == 0)
                k_finish<<<gF, bT, 0, stream>>>(T, XC, MVEC, SSst2, XC, XTd, nullptr, 1, 1);
            else
                k_finish<<<gF, bT, 0, stream>>>(T, XC, MVEC, SSst2, XC, nullptr, outp, 1, 0);
        }
    };

    if (nbat == 32) {
        // merged: train -> slots 0..15, test -> slots 16..31; out is contiguous [32][D][S]
        k_transpose_in<<<gT_in, bT, 0, stream>>>(train_feat, XC, XTd);
        k_transpose_in<<<gT_in, bT, 0, stream>>>(test_feat, XC + (size_t)NB * 2 * PB, XTd + (size_t)NB * PB);
        dec_layers(32, out);
    } else {
        k_transpose_in<<<gT_in, bT, 0, stream>>>(train_feat, XC, XTd);
        dec_layers(NB, out);
        k_transpose_in<<<gT_in, bT, 0, stream>>>(test_feat, XC, XTd);
        dec_layers(NB, out + SBD);
    }
}

// Round 18
// 875.356 us; speedup vs baseline: 1.5839x; 1.5839x over previous
//
#include <hip/hip_runtime.h>
#include <math.h>

#define NB 16
#define SEQ 1024
#define DM 512
#define KD 128
#define TEMP_F 30.0f
#define NS_F 0.011048543456039805f   // sqrt(1/8192)
#define DS_F 524288.0f               // D*H*W = 512*1024

// SS: per-stage slabs; 32 batch slots; one cache line per counter
#define SS_IDX(grp, b) (((grp) * 32 + (b)) * 16)
#define SS_STRIDE 1536
#define SS_STAGES 12
#define SS_FLOATS (SS_STRIDE * SS_STAGES)

// P scratch row stride (us): 144B rows, 16B-aligned b128 reads.
#define PSTR 72

typedef short bf16x8 __attribute__((ext_vector_type(8)));
typedef float f32x4 __attribute__((ext_vector_type(4)));
typedef unsigned short us;
typedef unsigned short us4v __attribute__((ext_vector_type(4)));
typedef unsigned short us8 __attribute__((ext_vector_type(8)));

__device__ __forceinline__ us f2bf(float x) {
    union { float f; unsigned u; } v; v.f = x;
    unsigned r = v.u + 0x7fffu + ((v.u >> 16) & 1u);
    return (us)(r >> 16);
}
__device__ __forceinline__ float bf2f(us h) {
    union { unsigned u; float f; } v; v.u = ((unsigned)h) << 16;
    return v.f;
}

// global -> LDS async 16B/lane. lds dst = wave-uniform base + lane*16 implicit.
#define GLL16(gp, lp) __builtin_amdgcn_global_load_lds( \
    (__attribute__((address_space(1))) void*)(unsigned long long)(gp), \
    (__attribute__((address_space(3))) void*)(unsigned)(unsigned long long)(lp), 16, 0, 0)

// ---------------- transpose in: src [16][D][S] f32 -> XC [.][S][1024] bf16 hi|lo + XT [.][D][S] bf16 ----------------
__global__ __launch_bounds__(256) void k_transpose_in(const float* __restrict__ src,
                                                      us* __restrict__ XC,
                                                      us* __restrict__ XT) {
    __shared__ float tile[32][33];
    const int b = blockIdx.z;
    const int d0 = blockIdx.x * 32;
    const int s0 = blockIdx.y * 32;
    const int tx = threadIdx.x, ty = threadIdx.y;  // 32x8
    const float* p = src + (size_t)b * DM * SEQ;
    us* pt = XT + (size_t)b * DM * SEQ;
    us* pc = XC + (size_t)b * SEQ * 1024;
#pragma unroll
    for (int j = 0; j < 32; j += 8) {
        const size_t o = (size_t)(d0 + ty + j) * SEQ + s0 + tx;
        const float v = p[o];
        tile[ty + j][tx] = v;
        pt[o] = f2bf(v);
    }
    __syncthreads();
#pragma unroll
    for (int j = 0; j < 4; ++j) {
        const int s = s0 + ty + j * 8;
        const int d = d0 + tx;
        const float v = tile[tx][ty + j * 8];
        const us h = f2bf(v);
        pc[(size_t)s * 1024 + d] = h;
        pc[(size_t)s * 1024 + 512 + d] = f2bf(v - bf2f(h));
    }
}

// ---------------- MEMLT[b][d][s] = MEMT[b][d][s] * label[b][s] ----------------
__global__ __launch_bounds__(256) void k_mklabel(const us* __restrict__ MT,
                                                 const float* __restrict__ label,
                                                 us* __restrict__ ML) {
    const int b = blockIdx.y;
    const size_t off = ((size_t)blockIdx.x * 256 + threadIdx.x) * 8;
    const int s = (int)(off & (SEQ - 1));
    const size_t o = (size_t)b * DM * SEQ + off;
    us8 v = *(const us8*)(MT + o);
    const float4 l0 = *(const float4*)(label + (size_t)b * SEQ + s);
    const float4 l1 = *(const float4*)(label + (size_t)b * SEQ + s + 4);
    us8 r;
    r[0] = f2bf(bf2f(v[0]) * l0.x); r[1] = f2bf(bf2f(v[1]) * l0.y);
    r[2] = f2bf(bf2f(v[2]) * l0.z); r[3] = f2bf(bf2f(v[3]) * l0.w);
    r[4] = f2bf(bf2f(v[4]) * l1.x); r[5] = f2bf(bf2f(v[5]) * l1.y);
    r[6] = f2bf(bf2f(v[6]) * l1.z); r[7] = f2bf(bf2f(v[7]) * l1.w);
    *(us8*)(ML + o) = r;
}

// ---------------- weight split: WK [DM][KD] f32 -> WC [KD][1024] bf16 hi|lo ----------------
__global__ __launch_bounds__(256) void k_wsplit(const float* __restrict__ WK,
                                                us* __restrict__ WC) {
    const int k = blockIdx.x;  // 0..KD
    for (int d = threadIdx.x; d < DM; d += 256) {
        const float v = WK[(size_t)d * KD + k];
        const us h = f2bf(v);
        WC[(size_t)k * 1024 + d] = h;
        WC[(size_t)k * 1024 + 512 + d] = f2bf(v - bf2f(h));
    }
}

// ---------------- projection GEMM: Wout[row][0:128]=hi,[128:256]=lo of l2norm(X@WK+bK) ----------------
__global__ __launch_bounds__(256) void k_proj(const us* __restrict__ XC,
                                              const us* __restrict__ WC,
                                              const float* __restrict__ bK,
                                              us* __restrict__ Wout) {
    const int row0 = blockIdx.x * 32;
    __shared__ short As[32 * 64], Bs[128 * 64];
    __shared__ float ssp[2][32];
    const int tid = threadIdx.x, w = tid >> 6, l = tid & 63;
    const int wm = (w >> 1) * 16, wn = (w & 1) * 64;
    const int sr = l >> 3, sc = (((l & 7) ^ (l >> 3)) << 3);
    const int lr = l & 15, lk = (l >> 4) * 8;
    const int sx = (lr & 7) << 3;
    f32x4 acc[4] = {};
    for (int k0 = 0; k0 < 1536; k0 += 64) {
        const int ak0 = (k0 < 1024) ? k0 : k0 - 1024;
        const int bk0 = (k0 < 512) ? k0 : k0 - 512;
        GLL16(XC + (size_t)(row0 + w * 8 + sr) * 1024 + ak0 + sc, &As[w * 512]);
#pragma unroll
        for (int cc = 0; cc < 4; ++cc) {
            const int c = 4 * w + cc;
            GLL16(WC + (size_t)(c * 8 + sr) * 1024 + bk0 + sc, &Bs[c * 512]);
        }
        __syncthreads();
#pragma unroll
        for (int kc = 0; kc < 2; ++kc) {
            const int kk = kc * 32 + lk;
            const bf16x8 a = *(const bf16x8*)&As[(wm + lr) * 64 + (kk ^ sx)];
            bf16x8 bb[4];
#pragma unroll
            for (int fn = 0; fn < 4; ++fn)
                bb[fn] = *(const bf16x8*)&Bs[(wn + fn * 16 + lr) * 64 + (kk ^ sx)];
#pragma unroll
            for (int fn = 0; fn < 4; ++fn)
                acc[fn] = __builtin_amdgcn_mfma_f32_16x16x32_bf16(a, bb[fn], acc[fn], 0, 0, 0);
        }
        __syncthreads();
    }
    const int er = l & 15, eq = (l >> 4) * 4;
    const int nh = w & 1;
    float bkv[4];
#pragma unroll
    for (int fn = 0; fn < 4; ++fn) bkv[fn] = bK[wn + fn * 16 + er];
    float vv[4][4];
#pragma unroll
    for (int r = 0; r < 4; ++r) {
        float ss = 0.f;
#pragma unroll
        for (int fn = 0; fn < 4; ++fn) {
            const float t = acc[fn][r] + bkv[fn];
            vv[fn][r] = t;
            ss += t * t;
        }
#pragma unroll
        for (int o = 8; o > 0; o >>= 1) ss += __shfl_xor(ss, o, 64);
        if (er == 0) ssp[nh][wm + eq + r] = ss;
    }
    __syncthreads();
#pragma unroll
    for (int r = 0; r < 4; ++r) {
        const int rowloc = wm + eq + r;
        const float tot = ssp[0][rowloc] + ssp[1][rowloc];
        const float invn = 1.0f / fmaxf(sqrtf(tot), 1e-12f);
        const size_t ro = (size_t)(row0 + rowloc) * 256;
#pragma unroll
        for (int fn = 0; fn < 4; ++fn) {
            const float ov = vv[fn][r] * invn;
            const us h = f2bf(ov);
            Wout[ro + wn + fn * 16 + er] = h;
            Wout[ro + 128 + wn + fn * 16 + er] = f2bf(ov - bf2f(h));
        }
    }
}

// ---------------- flash attention v8: 8 waves, q64, s64, swapped QK; K triple-buffered,
// P double-buffered -> ONE barrier per iter. V+label direct global. grid (nbat, 16). ----------------
__global__ __launch_bounds__(512, 1) void k_attn(const us* __restrict__ Qc,
                                                 const us* __restrict__ Kc,
                                                 const us* __restrict__ VT,
                                                 const us* __restrict__ XC,
                                                 const float* __restrict__ labelp,
                                                 float* __restrict__ MVEC,
                                                 float* __restrict__ Cout,
                                                 float* __restrict__ SS, int mode, int kvmask) {
    const int b = blockIdx.x;
    const int bkv = b & kvmask;
    const int q0 = blockIdx.y * 64;
    __shared__ short KL[3][4 * 64 * 64];     // 3x32 KB: K panels [p][64 s][64 k], col-XOR swizzle
    __shared__ us PL[2][64 * PSTR];          // 2x9 KB: P [64 q][64 s + pad]
    __shared__ float RSL[2][64], RLL[2][64];
    __shared__ float INVL[64], MVL[64];
    __shared__ float ps[3][8];
    const int tid = threadIdx.x, w = tid >> 6, l = tid & 63;
    const int lr = l & 15, g = l >> 4, lk = g * 8;
    const int qa = w & 3, sh = w >> 2;
    const int kx = (lr & 7) << 3;
    const us* Qb = Qc + (size_t)b * SEQ * 256;
    const us* Kb = Kc + (size_t)bkv * SEQ * 256;
    const us* Vb = VT + (size_t)bkv * DM * SEQ;
    const float* Lb = labelp ? labelp + (size_t)(bkv & 15) * SEQ : nullptr;

    // ---- Q fragments in registers (hi + lo) for this wave's 16 q (lane lr <-> q col) ----
    const us* Qrow = Qb + (size_t)(q0 + qa * 16 + lr) * 256;
    bf16x8 qh[4], ql[4];
#pragma unroll
    for (int kc = 0; kc < 4; ++kc) {
        qh[kc] = *(const bf16x8*)(Qrow + kc * 32 + lk);
        ql[kc] = *(const bf16x8*)(Qrow + 128 + kc * 32 + lk);
    }
    // ---- prologue: stage K tiles 0,1 (32 chunks each, 4/wave) ----
#pragma unroll
    for (int t = 0; t < 2; ++t)
#pragma unroll
        for (int i = 0; i < 4; ++i) {
            const int c = w * 4 + i, p = c & 3, rg = c >> 2;
            GLL16(Kb + (size_t)(t * 64 + rg * 8 + (l >> 3)) * 256 + p * 64 + (((l & 7) ^ (l >> 3)) << 3),
                  &KL[t][p * 4096 + rg * 512 + l * 8]);
        }
    __syncthreads();

    f32x4 acc[4][4];
#pragma unroll
    for (int m = 0; m < 4; ++m)
#pragma unroll
        for (int n = 0; n < 4; ++n) acc[m][n] = (f32x4){0.f, 0.f, 0.f, 0.f};
    float rs = 0.f, rl = 0.f;
    int cur = 0;   // KL index holding tile `it`
    for (int it = 0; it < 16; ++it) {
        const int s0 = it * 64;
        const int pb = it & 1;
        // ---- V fragments ks=0: direct global (hide under QK) ----
        bf16x8 vb0[4];
#pragma unroll
        for (int n = 0; n < 4; ++n)
            vb0[n] = *(const bf16x8*)(Vb + (size_t)(w * 64 + n * 16 + lr) * 1024 + s0 + lk);
        // ---- stage K tile it+2 into KL[(cur+2)%3] (its last reader was QK(it-1)) ----
        if (it < 14) {
            const int stg = (cur + 2 >= 3) ? cur - 1 : cur + 2;
            const int s2 = s0 + 128;
#pragma unroll
            for (int i = 0; i < 4; ++i) {
                const int c = w * 4 + i, p = c & 3, rg = c >> 2;
                GLL16(Kb + (size_t)(s2 + rg * 8 + (l >> 3)) * 256 + p * 64 + (((l & 7) ^ (l >> 3)) << 3),
                      &KL[stg][p * 4096 + rg * 512 + l * 8]);
            }
        }
        // ---- QK swapped: two 16q x 16s sub-tiles (sn) for (s-half sh, q-quarter qa) ----
        const short* KLc = KL[cur];
#pragma unroll
        for (int sn = 0; sn < 2; ++sn) {
            const int srow = sh * 32 + sn * 16 + lr;
            const int rowb = srow * 64;
            f32x4 sacc = {};
            bf16x8 kf[4];
#pragma unroll
            for (int kc = 0; kc < 4; ++kc)
                kf[kc] = *(const bf16x8*)&KLc[(kc >> 1) * 4096 + rowb + ((((kc & 1) << 5) + lk) ^ kx)];
            __builtin_amdgcn_s_setprio(1);
#pragma unroll
            for (int kc = 0; kc < 4; ++kc)
                sacc = __builtin_amdgcn_mfma_f32_16x16x32_bf16(kf[kc], qh[kc], sacc, 0, 0, 0);
#pragma unroll
            for (int kc = 0; kc < 4; ++kc)
                sacc = __builtin_amdgcn_mfma_f32_16x16x32_bf16(kf[kc], ql[kc], sacc, 0, 0, 0);
            __builtin_amdgcn_s_setprio(0);
#pragma unroll
            for (int kc = 0; kc < 4; ++kc)
                kf[kc] = *(const bf16x8*)&KLc[(2 + (kc >> 1)) * 4096 + rowb + ((((kc & 1) << 5) + lk) ^ kx)];
            __builtin_amdgcn_s_setprio(1);
#pragma unroll
            for (int kc = 0; kc < 4; ++kc)
                sacc = __builtin_amdgcn_mfma_f32_16x16x32_bf16(kf[kc], qh[kc], sacc, 0, 0, 0);
            __builtin_amdgcn_s_setprio(0);
            // exp + scalar rowsum partials + packed P write (lane: q=lr, s=sh*32+sn*16+g*4+r)
            const int sbase = sh * 32 + sn * 16 + g * 4;
            float lb4[4] = {0.f, 0.f, 0.f, 0.f};
            if (mode == 2) {
                const float4 t = *(const float4*)(Lb + s0 + sbase);
                lb4[0] = t.x; lb4[1] = t.y; lb4[2] = t.z; lb4[3] = t.w;
            }
            us4v pw;
#pragma unroll
            for (int r = 0; r < 4; ++r) {
                const float e = __expf(fmaf(TEMP_F, sacc[r], -TEMP_F));
                rs += e;
                rl += e * lb4[r];
                pw[r] = f2bf(e);
            }
            *(us4v*)&PL[pb][(qa * 16 + lr) * PSTR + sbase] = pw;
        }
        __syncthreads();   // P(it) visible; K stage(it-1) drained; V loads complete
        // ---- V fragments ks=1 (hidden under PV ks=0) ----
        bf16x8 vb1[4];
#pragma unroll
        for (int n = 0; n < 4; ++n)
            vb1[n] = *(const bf16x8*)(Vb + (size_t)(w * 64 + n * 16 + lr) * 1024 + s0 + 32 + lk);
        // ---- PV d-split: wave covers all 64 q x its 64-d slice; two ks steps ----
        const us* PLc = PL[pb];
        bf16x8 pa[4];
#pragma unroll
        for (int m = 0; m < 4; ++m)
            pa[m] = *(const bf16x8*)&PLc[(m * 16 + lr) * PSTR + lk];
        __builtin_amdgcn_s_setprio(1);
#pragma unroll
        for (int m = 0; m < 4; ++m)
#pragma unroll
            for (int n = 0; n < 4; ++n)
                acc[m][n] = __builtin_amdgcn_mfma_f32_16x16x32_bf16(pa[m], vb0[n], acc[m][n], 0, 0, 0);
        __builtin_amdgcn_s_setprio(0);
#pragma unroll
        for (int m = 0; m < 4; ++m)
            pa[m] = *(const bf16x8*)&PLc[(m * 16 + lr) * PSTR + 32 + lk];
        __builtin_amdgcn_s_setprio(1);
#pragma unroll
        for (int m = 0; m < 4; ++m)
#pragma unroll
            for (int n = 0; n < 4; ++n)
                acc[m][n] = __builtin_amdgcn_mfma_f32_16x16x32_bf16(pa[m], vb1[n], acc[m][n], 0, 0, 0);
        __builtin_amdgcn_s_setprio(0);
        cur = (cur + 1 >= 3) ? 0 : cur + 1;
        // no end-of-iter barrier: next QK's KL buffer was drained one barrier ago,
        // and next QK's PL buffer was last read two barriers ago.
    }

    // ---- rowsum combine: cross-g shfl, then cross s-half via LDS ----
    rs += __shfl_xor(rs, 16, 64);
    rs += __shfl_xor(rs, 32, 64);
    rl += __shfl_xor(rl, 16, 64);
    rl += __shfl_xor(rl, 32, 64);
    __syncthreads();   // all PV reads of PL done before RSL/RLL overlay writes (distinct arrays, but order anyway)
    if (g == 0) {
        RSL[sh][qa * 16 + lr] = rs;
        RLL[sh][qa * 16 + lr] = rl;
    }
    __syncthreads();
    if (tid < 64) {
        const float tot = RSL[0][tid] + RSL[1][tid];
        const float iv = 1.0f / tot;
        INVL[tid] = iv;
        const float mvv = (RLL[0][tid] + RLL[1][tid]) * iv;
        MVL[tid] = mvv;
        if (mode == 2) MVEC[(size_t)b * SEQ + q0 + tid] = mvv;
    }
    __syncthreads();

    // ---- epilogue: normalize, residual, SS ----
    const us* XCb = XC + (size_t)b * SEQ * 1024;
    float sa = 0.f, sb = 0.f, sab = 0.f;
#pragma unroll
    for (int m = 0; m < 4; ++m)
#pragma unroll
        for (int r = 0; r < 4; ++r) {
            const int q = m * 16 + g * 4 + r;
            const float iv = INVL[q];
            const float mvq = MVL[q];
            const int row = q0 + q;
#pragma unroll
            for (int n = 0; n < 4; ++n) {
                const int col = w * 64 + n * 16 + lr;
                float v = acc[m][n][r] * iv;
                const size_t o = ((size_t)b * SEQ + row) * DM + col;
                const size_t xo = (size_t)row * 1024 + col;
                const float x = bf2f(XCb[xo]) + bf2f(XCb[xo + 512]);
                v += x;
                sb += v * v;
                if (mode == 2) { const float a = x * mvq; sa += a * a; sab += a * v; }
                Cout[o] = v;
            }
        }
#pragma unroll
    for (int off = 32; off > 0; off >>= 1) {
        sb += __shfl_xor(sb, off, 64);
        if (mode == 2) { sa += __shfl_xor(sa, off, 64); sab += __shfl_xor(sab, off, 64); }
    }
    if (l == 0) { ps[0][w] = sb; ps[1][w] = sa; ps[2][w] = sab; }
    __syncthreads();
    if (tid == 0) {
        float t0 = 0.f, t1 = 0.f, t2 = 0.f;
#pragma unroll
        for (int i = 0; i < 8; ++i) { t0 += ps[0][i]; t1 += ps[1][i]; t2 += ps[2][i]; }
        if (mode == 1) {
            atomicAdd(&SS[SS_IDX(0, b)], t0);
        } else {
            atomicAdd(&SS[SS_IDX(0, b)], t1);
            atomicAdd(&SS[SS_IDX(1, b)], t0);
            atomicAdd(&SS[SS_IDX(2, b)], t2);
        }
    }
}

// ---------------- zero all SS stages ----------------
__global__ void k_zero(float* __restrict__ SSb) {
    const int i = blockIdx.x * 256 + threadIdx.x;
    if (i < SS_FLOATS) SSb[i] = 0.0f;
}

// ---------------- finish: v from T (+XC), write XC hi|lo + transposed bf16/f32 ----------------
// mode 0: v = f3*T ; mode 1: v = f3*(f1*x*mv + f2*T)  (T holds x+t3)
__global__ __launch_bounds__(256) void k_finish(const float* __restrict__ Tin,
                                                const us* __restrict__ XCin,
                                                const float* __restrict__ mv,
                                                const float* __restrict__ SS,
                                                us* __restrict__ XCout,
                                                us* __restrict__ XTb,
                                                float* __restrict__ XTf,
                                                int mode, int writeXC) {
    const int b = blockIdx.z;
    const int s0 = blockIdx.x * 32, d0 = blockIdx.y * 32;
    const int tx = threadIdx.x, ty = threadIdx.y;
    __shared__ float tile[32][33];
    float f1 = 0.f, f2 = 0.f, f3;
    if (mode == 0) {
        f3 = NS_F * sqrtf(DS_F / (SS[SS_IDX(0, b)] + 1e-5f));
    } else {
        const float ssa = SS[SS_IDX(0, b)], ssb = SS[SS_IDX(1, b)], ssab = SS[SS_IDX(2, b)];
        f1 = NS_F * sqrtf(DS_F / (ssa + 1e-5f));
        f2 = NS_F * sqrtf(DS_F / (ssb + 1e-5f));
        const float ssc = f1 * f1 * ssa + 2.f * f1 * f2 * ssab + f2 * f2 * ssb;
        f3 = NS_F * sqrtf(DS_F / (ssc + 1e-5f));
    }
#pragma unroll
    for (int j = 0; j < 4; ++j) {
        const int s = s0 + ty + j * 8;
        const int d = d0 + tx;
        const size_t o = ((size_t)b * SEQ + s) * DM + d;
        const size_t xo = ((size_t)b * SEQ + s) * 1024 + d;
        float v;
        if (mode == 0) v = f3 * Tin[o];
        else {
            const float x = bf2f(XCin[xo]) + bf2f(XCin[xo + 512]);
            v = f3 * (f1 * x * mv[(size_t)b * SEQ + s] + f2 * Tin[o]);
        }
        if (writeXC) {
            const us h = f2bf(v);
            XCout[xo] = h;
            XCout[xo + 512] = f2bf(v - bf2f(h));
        }
        tile[ty + j * 8][tx] = v;
    }
    __syncthreads();
#pragma unroll
    for (int j = 0; j < 4; ++j) {
        const int d = d0 + ty + j * 8;
        const int s = s0 + tx;
        const float v = tile[tx][ty + j * 8];
        const size_t o = ((size_t)b * DM + d) * SEQ + s;
        if (XTb) XTb[o] = f2bf(v);
        else if (XTf) XTf[o] = v;
    }
}

extern "C" void kernel_launch(void* const* d_in, const int* in_sizes, int n_in,
                              void* d_out, int out_size, void* d_ws, size_t ws_size,
                              hipStream_t stream) {
    const float* train_feat = (const float*)d_in[0];
    const float* test_feat  = (const float*)d_in[1];
    const float* label      = (const float*)d_in[2];
    const float* WKs        = (const float*)d_in[3];
    const float* bKs        = (const float*)d_in[4];
    const float* WKc        = (const float*)d_in[5];
    const float* bKc        = (const float*)d_in[6];
    float* out = (float*)d_out;
    float* w = (float*)d_ws;

    const size_t PB  = (size_t)SEQ * DM;        // 524,288 elems per batch
    const size_t SBD = (size_t)NB * PB;         // 16-batch slab

    // choose merged (32-batch stream) if workspace allows
    auto needF = [&](size_t nbat) {
        return nbat * (PB /*T*/ + PB /*XC(us2)*/ + PB / 2 /*XTd*/ + PB / 4 /*W1C*/ + 1024 /*MVEC*/)
             + (size_t)NB * (PB / 2 /*MEMT*/ + PB / 2 /*MEMLT*/ + PB / 4 /*WKMC*/)
             + 2 * (size_t)KD * 512 /*WCs+WCc*/ + SS_FLOATS + 4096;
    };
    const size_t wsf = ws_size / 4;
    const int nbat = (wsf >= needF(32)) ? 32 : NB;

    float* T    = w;                                   // nbat*PB f32
    us* XC      = (us*)(T + (size_t)nbat * PB);        // nbat*2*PB us (hi|lo)
    us* XTd     = XC + (size_t)nbat * 2 * PB;          // nbat*PB us
    us* W1C     = XTd + (size_t)nbat * PB;             // nbat*PB/2 us
    us* MEMT    = W1C + (size_t)nbat * PB / 2;         // NB*PB us
    us* MEMLT   = MEMT + (size_t)NB * PB;              // NB*PB us
    us* WKMC    = MEMLT + (size_t)NB * PB;             // NB*PB/2 us
    us* WCs     = WKMC + (size_t)NB * PB / 2;          // KD*1024 us
    us* WCc     = WCs + (size_t)KD * 1024;
    float* MVEC = (float*)(WCc + (size_t)KD * 1024);   // nbat*SEQ f32
    float* SS   = MVEC + (size_t)nbat * SEQ;           // SS_FLOATS

    const dim3 gT_in(DM / 32, SEQ / 32, NB), bT(32, 8);

    int stage = 0;
    auto nextSS = [&]() { return SS + (size_t)(stage++) * SS_STRIDE; };

    // ---------------- setup ----------------
    k_zero<<<(SS_FLOATS + 255) / 256, 256, 0, stream>>>(SS);
    k_wsplit<<<KD, 256, 0, stream>>>(WKs, WCs);
    k_wsplit<<<KD, 256, 0, stream>>>(WKc, WCc);

    // ---------------- encoder (16 batches, in first 16 slots) ----------------
    k_transpose_in<<<gT_in, bT, 0, stream>>>(train_feat, XC, MEMT);
    for (int l = 0; l < 2; ++l) {
        float* SSst = nextSS();
        k_proj<<<NB * SEQ / 32, 256, 0, stream>>>(XC, WCs, bKs, W1C);
        k_attn<<<dim3(NB, SEQ / 64), 512, 0, stream>>>(W1C, W1C, MEMT, XC, nullptr, nullptr, T, SSst, 1, 63);
        k_finish<<<dim3(SEQ / 32, DM / 32, NB), bT, 0, stream>>>(T, XC, nullptr, SSst, XC, MEMT, nullptr, 0, 1);
    }
    k_proj<<<NB * SEQ / 32, 256, 0, stream>>>(XC, WCc, bKc, WKMC);
    k_mklabel<<<dim3(DM * SEQ / 8 / 256, NB), 256, 0, stream>>>(MEMT, label, MEMLT);

    // ---------------- decoder stages over `db` batches starting at slot 0 ----------------
    auto dec_layers = [&](int db, float* outp) {
        const dim3 gA(db, SEQ / 64);
        const dim3 gF(SEQ / 32, DM / 32, db);
        for (int l = 0; l < 2; ++l) {
            // self-attn + inorm
            float* SSst = nextSS();
            k_proj<<<db * SEQ / 32, 256, 0, stream>>>(XC, WCs, bKs, W1C);
            k_attn<<<gA, 512, 0, stream>>>(W1C, W1C, XTd, XC, nullptr, nullptr, T, SSst, 1, 63);
            k_finish<<<gF, bT, 0, stream>>>(T, XC, nullptr, SSst, XC, XTd, nullptr, 0, 1);
            // cross-attn (fused reduce3): T = x + t3; SS = ssa/ssb/ssab; MVEC = mask
            float* SSst2 = nextSS();
            k_proj<<<db * SEQ / 32, 256, 0, stream>>>(XC, WCc, bKc, W1C);
            k_attn<<<gA, 512, 0, stream>>>(W1C, WKMC, MEMLT, XC, label, MVEC, T, SSst2, 2, 15);
            // fused triple instance-norm finish
            if (l == 0)
                k_finish<<<gF, bT, 0, stream>>>(T, XC, MVEC, SSst2, XC, XTd, nullptr, 1, 1);
            else
                k_finish<<<gF, bT, 0, stream>>>(T, XC, MVEC, SSst2, XC, nullptr, outp, 1, 0);
        }
    };

    if (nbat == 32) {
        // merged: train -> slots 0..15, test -> slots 16..31; out is contiguous [32][D][S]
        k_transpose_in<<<gT_in, bT, 0, stream>>>(train_feat, XC, XTd);
        k_transpose_in<<<gT_in, bT, 0, stream>>>(test_feat, XC + (size_t)NB * 2 * PB, XTd + (size_t)NB * PB);
        dec_layers(32, out);
    } else {
        k_transpose_in<<<gT_in, bT, 0, stream>>>(train_feat, XC, XTd);
        dec_layers(NB, out);
        k_transpose_in<<<gT_in, bT, 0, stream>>>(test_feat, XC, XTd);
        dec_layers(NB, out + SBD);
    }
}

// Round 19
// 870.988 us; speedup vs baseline: 1.5918x; 1.0050x over previous
//
#include <hip/hip_runtime.h>
#include <math.h>

#define NB 16
#define SEQ 1024
#define DM 512
#define KD 128
#define TEMP_F 30.0f
#define NS_F 0.011048543456039805f   // sqrt(1/8192)
#define DS_F 524288.0f               // D*H*W = 512*1024

// SS: per-stage slabs; 32 batch slots; one cache line per counter
#define SS_IDX(grp, b) (((grp) * 32 + (b)) * 16)
#define SS_STRIDE 1536
#define SS_STAGES 12
#define SS_FLOATS (SS_STRIDE * SS_STAGES)

// P scratch row stride (us): 144B rows, 16B-aligned b128 reads.
#define PSTR 72

typedef short bf16x8 __attribute__((ext_vector_type(8)));
typedef float f32x4 __attribute__((ext_vector_type(4)));
typedef unsigned short us;
typedef unsigned short us4v __attribute__((ext_vector_type(4)));
typedef unsigned short us8 __attribute__((ext_vector_type(8)));

__device__ __forceinline__ us f2bf(float x) {
    union { float f; unsigned u; } v; v.f = x;
    unsigned r = v.u + 0x7fffu + ((v.u >> 16) & 1u);
    return (us)(r >> 16);
}
__device__ __forceinline__ float bf2f(us h) {
    union { unsigned u; float f; } v; v.u = ((unsigned)h) << 16;
    return v.f;
}

// global -> LDS async 16B/lane. lds dst = wave-uniform base + lane*16 implicit.
#define GLL16(gp, lp) __builtin_amdgcn_global_load_lds( \
    (__attribute__((address_space(1))) void*)(unsigned long long)(gp), \
    (__attribute__((address_space(3))) void*)(unsigned)(unsigned long long)(lp), 16, 0, 0)

// ---------------- transpose in: src [16][D][S] f32 -> XC [.][S][1024] bf16 hi|lo + XT [.][D][S] bf16 ----------------
__global__ __launch_bounds__(256) void k_transpose_in(const float* __restrict__ src,
                                                      us* __restrict__ XC,
                                                      us* __restrict__ XT) {
    __shared__ float tile[32][33];
    const int b = blockIdx.z;
    const int d0 = blockIdx.x * 32;
    const int s0 = blockIdx.y * 32;
    const int tx = threadIdx.x, ty = threadIdx.y;  // 32x8
    const float* p = src + (size_t)b * DM * SEQ;
    us* pt = XT + (size_t)b * DM * SEQ;
    us* pc = XC + (size_t)b * SEQ * 1024;
#pragma unroll
    for (int j = 0; j < 32; j += 8) {
        const size_t o = (size_t)(d0 + ty + j) * SEQ + s0 + tx;
        const float v = p[o];
        tile[ty + j][tx] = v;
        pt[o] = f2bf(v);
    }
    __syncthreads();
#pragma unroll
    for (int j = 0; j < 4; ++j) {
        const int s = s0 + ty + j * 8;
        const int d = d0 + tx;
        const float v = tile[tx][ty + j * 8];
        const us h = f2bf(v);
        pc[(size_t)s * 1024 + d] = h;
        pc[(size_t)s * 1024 + 512 + d] = f2bf(v - bf2f(h));
    }
}

// ---------------- MEMLT[b][d][s] = MEMT[b][d][s] * label[b][s] ----------------
__global__ __launch_bounds__(256) void k_mklabel(const us* __restrict__ MT,
                                                 const float* __restrict__ label,
                                                 us* __restrict__ ML) {
    const int b = blockIdx.y;
    const size_t off = ((size_t)blockIdx.x * 256 + threadIdx.x) * 8;
    const int s = (int)(off & (SEQ - 1));
    const size_t o = (size_t)b * DM * SEQ + off;
    us8 v = *(const us8*)(MT + o);
    const float4 l0 = *(const float4*)(label + (size_t)b * SEQ + s);
    const float4 l1 = *(const float4*)(label + (size_t)b * SEQ + s + 4);
    us8 r;
    r[0] = f2bf(bf2f(v[0]) * l0.x); r[1] = f2bf(bf2f(v[1]) * l0.y);
    r[2] = f2bf(bf2f(v[2]) * l0.z); r[3] = f2bf(bf2f(v[3]) * l0.w);
    r[4] = f2bf(bf2f(v[4]) * l1.x); r[5] = f2bf(bf2f(v[5]) * l1.y);
    r[6] = f2bf(bf2f(v[6]) * l1.z); r[7] = f2bf(bf2f(v[7]) * l1.w);
    *(us8*)(ML + o) = r;
}

// ---------------- weight split: WK [DM][KD] f32 -> WC [KD][1024] bf16 hi|lo ----------------
__global__ __launch_bounds__(256) void k_wsplit(const float* __restrict__ WK,
                                                us* __restrict__ WC) {
    const int k = blockIdx.x;  // 0..KD
    for (int d = threadIdx.x; d < DM; d += 256) {
        const float v = WK[(size_t)d * KD + k];
        const us h = f2bf(v);
        WC[(size_t)k * 1024 + d] = h;
        WC[(size_t)k * 1024 + 512 + d] = f2bf(v - bf2f(h));
    }
}

// ---------------- projection GEMM: Wout[row][0:128]=hi,[128:256]=lo of l2norm(X@WK+bK) ----------------
__global__ __launch_bounds__(256) void k_proj(const us* __restrict__ XC,
                                              const us* __restrict__ WC,
                                              const float* __restrict__ bK,
                                              us* __restrict__ Wout) {
    const int row0 = blockIdx.x * 32;
    __shared__ short As[32 * 64], Bs[128 * 64];
    __shared__ float ssp[2][32];
    const int tid = threadIdx.x, w = tid >> 6, l = tid & 63;
    const int wm = (w >> 1) * 16, wn = (w & 1) * 64;
    const int sr = l >> 3, sc = (((l & 7) ^ (l >> 3)) << 3);
    const int lr = l & 15, lk = (l >> 4) * 8;
    const int sx = (lr & 7) << 3;
    f32x4 acc[4] = {};
    for (int k0 = 0; k0 < 1536; k0 += 64) {
        const int ak0 = (k0 < 1024) ? k0 : k0 - 1024;
        const int bk0 = (k0 < 512) ? k0 : k0 - 512;
        GLL16(XC + (size_t)(row0 + w * 8 + sr) * 1024 + ak0 + sc, &As[w * 512]);
#pragma unroll
        for (int cc = 0; cc < 4; ++cc) {
            const int c = 4 * w + cc;
            GLL16(WC + (size_t)(c * 8 + sr) * 1024 + bk0 + sc, &Bs[c * 512]);
        }
        __syncthreads();
#pragma unroll
        for (int kc = 0; kc < 2; ++kc) {
            const int kk = kc * 32 + lk;
            const bf16x8 a = *(const bf16x8*)&As[(wm + lr) * 64 + (kk ^ sx)];
            bf16x8 bb[4];
#pragma unroll
            for (int fn = 0; fn < 4; ++fn)
                bb[fn] = *(const bf16x8*)&Bs[(wn + fn * 16 + lr) * 64 + (kk ^ sx)];
#pragma unroll
            for (int fn = 0; fn < 4; ++fn)
                acc[fn] = __builtin_amdgcn_mfma_f32_16x16x32_bf16(a, bb[fn], acc[fn], 0, 0, 0);
        }
        __syncthreads();
    }
    const int er = l & 15, eq = (l >> 4) * 4;
    const int nh = w & 1;
    float bkv[4];
#pragma unroll
    for (int fn = 0; fn < 4; ++fn) bkv[fn] = bK[wn + fn * 16 + er];
    float vv[4][4];
#pragma unroll
    for (int r = 0; r < 4; ++r) {
        float ss = 0.f;
#pragma unroll
        for (int fn = 0; fn < 4; ++fn) {
            const float t = acc[fn][r] + bkv[fn];
            vv[fn][r] = t;
            ss += t * t;
        }
#pragma unroll
        for (int o = 8; o > 0; o >>= 1) ss += __shfl_xor(ss, o, 64);
        if (er == 0) ssp[nh][wm + eq + r] = ss;
    }
    __syncthreads();
#pragma unroll
    for (int r = 0; r < 4; ++r) {
        const int rowloc = wm + eq + r;
        const float tot = ssp[0][rowloc] + ssp[1][rowloc];
        const float invn = 1.0f / fmaxf(sqrtf(tot), 1e-12f);
        const size_t ro = (size_t)(row0 + rowloc) * 256;
#pragma unroll
        for (int fn = 0; fn < 4; ++fn) {
            const float ov = vv[fn][r] * invn;
            const us h = f2bf(ov);
            Wout[ro + wn + fn * 16 + er] = h;
            Wout[ro + 128 + wn + fn * 16 + er] = f2bf(ov - bf2f(h));
        }
    }
}

// ---------------- flash attention v10: v8 + QK ILP (6 independent MFMA chains of depth 4). ----------------
__global__ __launch_bounds__(512, 1) void k_attn(const us* __restrict__ Qc,
                                                 const us* __restrict__ Kc,
                                                 const us* __restrict__ VT,
                                                 const us* __restrict__ XC,
                                                 const float* __restrict__ labelp,
                                                 float* __restrict__ MVEC,
                                                 float* __restrict__ Cout,
                                                 float* __restrict__ SS, int mode, int kvmask) {
    const int b = blockIdx.x;
    const int bkv = b & kvmask;
    const int q0 = blockIdx.y * 64;
    __shared__ short KL[3][4 * 64 * 64];     // 3x32 KB: K panels [p][64 s][64 k], col-XOR swizzle
    __shared__ us PL[2][64 * PSTR];          // 2x9 KB: P [64 q][64 s + pad]
    __shared__ float RSL[2][64], RLL[2][64];
    __shared__ float INVL[64], MVL[64];
    __shared__ float ps[3][8];
    const int tid = threadIdx.x, w = tid >> 6, l = tid & 63;
    const int lr = l & 15, g = l >> 4, lk = g * 8;
    const int qa = w & 3, sh = w >> 2;
    const int kx = (lr & 7) << 3;
    const us* Qb = Qc + (size_t)b * SEQ * 256;
    const us* Kb = Kc + (size_t)bkv * SEQ * 256;
    const us* Vb = VT + (size_t)bkv * DM * SEQ;
    const float* Lb = labelp ? labelp + (size_t)(bkv & 15) * SEQ : nullptr;

    // ---- Q fragments in registers (hi + lo) for this wave's 16 q (lane lr <-> q col) ----
    const us* Qrow = Qb + (size_t)(q0 + qa * 16 + lr) * 256;
    bf16x8 qh[4], ql[4];
#pragma unroll
    for (int kc = 0; kc < 4; ++kc) {
        qh[kc] = *(const bf16x8*)(Qrow + kc * 32 + lk);
        ql[kc] = *(const bf16x8*)(Qrow + 128 + kc * 32 + lk);
    }
    // ---- prologue: stage K tiles 0,1 (32 chunks each, 4/wave) ----
#pragma unroll
    for (int t = 0; t < 2; ++t)
#pragma unroll
        for (int i = 0; i < 4; ++i) {
            const int c = w * 4 + i, p = c & 3, rg = c >> 2;
            GLL16(Kb + (size_t)(t * 64 + rg * 8 + (l >> 3)) * 256 + p * 64 + (((l & 7) ^ (l >> 3)) << 3),
                  &KL[t][p * 4096 + rg * 512 + l * 8]);
        }
    __syncthreads();

    f32x4 acc[4][4];
#pragma unroll
    for (int m = 0; m < 4; ++m)
#pragma unroll
        for (int n = 0; n < 4; ++n) acc[m][n] = (f32x4){0.f, 0.f, 0.f, 0.f};
    float rs = 0.f, rl = 0.f;
    int cur = 0;   // KL index holding tile `it`
    for (int it = 0; it < 16; ++it) {
        const int s0 = it * 64;
        const int pb = it & 1;
        // ---- V fragments ks=0: direct global (hide under QK) ----
        bf16x8 vb0[4];
#pragma unroll
        for (int n = 0; n < 4; ++n)
            vb0[n] = *(const bf16x8*)(Vb + (size_t)(w * 64 + n * 16 + lr) * 1024 + s0 + lk);
        // ---- stage K tile it+2 into KL[(cur+2)%3] (its last reader was QK(it-1)) ----
        if (it < 14) {
            const int stg = (cur + 2 >= 3) ? cur - 1 : cur + 2;
            const int s2 = s0 + 128;
#pragma unroll
            for (int i = 0; i < 4; ++i) {
                const int c = w * 4 + i, p = c & 3, rg = c >> 2;
                GLL16(Kb + (size_t)(s2 + rg * 8 + (l >> 3)) * 256 + p * 64 + (((l & 7) ^ (l >> 3)) << 3),
                      &KL[stg][p * 4096 + rg * 512 + l * 8]);
            }
        }
        // ---- QK swapped: both sn sub-tiles interleaved; 3-way split accumulators ----
        const short* KLc = KL[cur];
        bf16x8 kf[2][4];
#pragma unroll
        for (int sn = 0; sn < 2; ++sn)
#pragma unroll
            for (int kc = 0; kc < 4; ++kc)
                kf[sn][kc] = *(const bf16x8*)&KLc[(kc >> 1) * 4096 + (sh * 32 + sn * 16 + lr) * 64 +
                                                 ((((kc & 1) << 5) + lk) ^ kx)];
        f32x4 sA[2] = {}, sB[2] = {}, sC[2] = {};
        __builtin_amdgcn_s_setprio(1);
#pragma unroll
        for (int kc = 0; kc < 4; ++kc) {
            sA[0] = __builtin_amdgcn_mfma_f32_16x16x32_bf16(kf[0][kc], qh[kc], sA[0], 0, 0, 0);
            sA[1] = __builtin_amdgcn_mfma_f32_16x16x32_bf16(kf[1][kc], qh[kc], sA[1], 0, 0, 0);
            sB[0] = __builtin_amdgcn_mfma_f32_16x16x32_bf16(kf[0][kc], ql[kc], sB[0], 0, 0, 0);
            sB[1] = __builtin_amdgcn_mfma_f32_16x16x32_bf16(kf[1][kc], ql[kc], sB[1], 0, 0, 0);
        }
        __builtin_amdgcn_s_setprio(0);
#pragma unroll
        for (int sn = 0; sn < 2; ++sn)
#pragma unroll
            for (int kc = 0; kc < 4; ++kc)
                kf[sn][kc] = *(const bf16x8*)&KLc[(2 + (kc >> 1)) * 4096 + (sh * 32 + sn * 16 + lr) * 64 +
                                                 ((((kc & 1) << 5) + lk) ^ kx)];
        __builtin_amdgcn_s_setprio(1);
#pragma unroll
        for (int kc = 0; kc < 4; ++kc) {
            sC[0] = __builtin_amdgcn_mfma_f32_16x16x32_bf16(kf[0][kc], qh[kc], sC[0], 0, 0, 0);
            sC[1] = __builtin_amdgcn_mfma_f32_16x16x32_bf16(kf[1][kc], qh[kc], sC[1], 0, 0, 0);
        }
        __builtin_amdgcn_s_setprio(0);
        // ---- exp + scalar rowsum partials + packed P write (lane: q=lr, s=sh*32+sn*16+g*4+r) ----
#pragma unroll
        for (int sn = 0; sn < 2; ++sn) {
            const f32x4 sacc = sA[sn] + sB[sn] + sC[sn];
            const int sbase = sh * 32 + sn * 16 + g * 4;
            float lb4[4] = {0.f, 0.f, 0.f, 0.f};
            if (mode == 2) {
                const float4 t = *(const float4*)(Lb + s0 + sbase);
                lb4[0] = t.x; lb4[1] = t.y; lb4[2] = t.z; lb4[3] = t.w;
            }
            us4v pw;
#pragma unroll
            for (int r = 0; r < 4; ++r) {
                const float e = __expf(fmaf(TEMP_F, sacc[r], -TEMP_F));
                rs += e;
                rl += e * lb4[r];
                pw[r] = f2bf(e);
            }
            *(us4v*)&PL[pb][(qa * 16 + lr) * PSTR + sbase] = pw;
        }
        __syncthreads();   // P(it) visible; K stage(it-1) drained; V loads complete
        // ---- V fragments ks=1 (hidden under PV ks=0) ----
        bf16x8 vb1[4];
#pragma unroll
        for (int n = 0; n < 4; ++n)
            vb1[n] = *(const bf16x8*)(Vb + (size_t)(w * 64 + n * 16 + lr) * 1024 + s0 + 32 + lk);
        // ---- PV d-split: wave covers all 64 q x its 64-d slice; two ks steps ----
        const us* PLc = PL[pb];
        bf16x8 pa[4];
#pragma unroll
        for (int m = 0; m < 4; ++m)
            pa[m] = *(const bf16x8*)&PLc[(m * 16 + lr) * PSTR + lk];
        __builtin_amdgcn_s_setprio(1);
#pragma unroll
        for (int m = 0; m < 4; ++m)
#pragma unroll
            for (int n = 0; n < 4; ++n)
                acc[m][n] = __builtin_amdgcn_mfma_f32_16x16x32_bf16(pa[m], vb0[n], acc[m][n], 0, 0, 0);
        __builtin_amdgcn_s_setprio(0);
#pragma unroll
        for (int m = 0; m < 4; ++m)
            pa[m] = *(const bf16x8*)&PLc[(m * 16 + lr) * PSTR + 32 + lk];
        __builtin_amdgcn_s_setprio(1);
#pragma unroll
        for (int m = 0; m < 4; ++m)
#pragma unroll
            for (int n = 0; n < 4; ++n)
                acc[m][n] = __builtin_amdgcn_mfma_f32_16x16x32_bf16(pa[m], vb1[n], acc[m][n], 0, 0, 0);
        __builtin_amdgcn_s_setprio(0);
        cur = (cur + 1 >= 3) ? 0 : cur + 1;
        // no end-of-iter barrier: next QK's KL buffer was drained one barrier ago,
        // and next QK's PL buffer was last read two barriers ago.
    }

    // ---- rowsum combine: cross-g shfl, then cross s-half via LDS ----
    rs += __shfl_xor(rs, 16, 64);
    rs += __shfl_xor(rs, 32, 64);
    rl += __shfl_xor(rl, 16, 64);
    rl += __shfl_xor(rl, 32, 64);
    __syncthreads();
    if (g == 0) {
        RSL[sh][qa * 16 + lr] = rs;
        RLL[sh][qa * 16 + lr] = rl;
    }
    __syncthreads();
    if (tid < 64) {
        const float tot = RSL[0][tid] + RSL[1][tid];
        const float iv = 1.0f / tot;
        INVL[tid] = iv;
        const float mvv = (RLL[0][tid] + RLL[1][tid]) * iv;
        MVL[tid] = mvv;
        if (mode == 2) MVEC[(size_t)b * SEQ + q0 + tid] = mvv;
    }
    __syncthreads();

    // ---- epilogue: normalize, residual, SS ----
    const us* XCb = XC + (size_t)b * SEQ * 1024;
    float sa = 0.f, sb = 0.f, sab = 0.f;
#pragma unroll
    for (int m = 0; m < 4; ++m)
#pragma unroll
        for (int r = 0; r < 4; ++r) {
            const int q = m * 16 + g * 4 + r;
            const float iv = INVL[q];
            const float mvq = MVL[q];
            const int row = q0 + q;
#pragma unroll
            for (int n = 0; n < 4; ++n) {
                const int col = w * 64 + n * 16 + lr;
                float v = acc[m][n][r] * iv;
                const size_t o = ((size_t)b * SEQ + row) * DM + col;
                const size_t xo = (size_t)row * 1024 + col;
                const float x = bf2f(XCb[xo]) + bf2f(XCb[xo + 512]);
                v += x;
                sb += v * v;
                if (mode == 2) { const float a = x * mvq; sa += a * a; sab += a * v; }
                Cout[o] = v;
            }
        }
#pragma unroll
    for (int off = 32; off > 0; off >>= 1) {
        sb += __shfl_xor(sb, off, 64);
        if (mode == 2) { sa += __shfl_xor(sa, off, 64); sab += __shfl_xor(sab, off, 64); }
    }
    if (l == 0) { ps[0][w] = sb; ps[1][w] = sa; ps[2][w] = sab; }
    __syncthreads();
    if (tid == 0) {
        float t0 = 0.f, t1 = 0.f, t2 = 0.f;
#pragma unroll
        for (int i = 0; i < 8; ++i) { t0 += ps[0][i]; t1 += ps[1][i]; t2 += ps[2][i]; }
        if (mode == 1) {
            atomicAdd(&SS[SS_IDX(0, b)], t0);
        } else {
            atomicAdd(&SS[SS_IDX(0, b)], t1);
            atomicAdd(&SS[SS_IDX(1, b)], t0);
            atomicAdd(&SS[SS_IDX(2, b)], t2);
        }
    }
}

// ---------------- zero all SS stages ----------------
__global__ void k_zero(float* __restrict__ SSb) {
    const int i = blockIdx.x * 256 + threadIdx.x;
    if (i < SS_FLOATS) SSb[i] = 0.0f;
}

// ---------------- finish: v from T (+XC), write XC hi|lo + transposed bf16/f32 ----------------
// mode 0: v = f3*T ; mode 1: v = f3*(f1*x*mv + f2*T)  (T holds x+t3)
__global__ __launch_bounds__(256) void k_finish(const float* __restrict__ Tin,
                                                const us* __restrict__ XCin,
                                                const float* __restrict__ mv,
                                                const float* __restrict__ SS,
                                                us* __restrict__ XCout,
                                                us* __restrict__ XTb,
                                                float* __restrict__ XTf,
                                                int mode, int writeXC) {
    const int b = blockIdx.z;
    const int s0 = blockIdx.x * 32, d0 = blockIdx.y * 32;
    const int tx = threadIdx.x, ty = threadIdx.y;
    __shared__ float tile[32][33];
    float f1 = 0.f, f2 = 0.f, f3;
    if (mode == 0) {
        f3 = NS_F * sqrtf(DS_F / (SS[SS_IDX(0, b)] + 1e-5f));
    } else {
        const float ssa = SS[SS_IDX(0, b)], ssb = SS[SS_IDX(1, b)], ssab = SS[SS_IDX(2, b)];
        f1 = NS_F * sqrtf(DS_F / (ssa + 1e-5f));
        f2 = NS_F * sqrtf(DS_F / (ssb + 1e-5f));
        const float ssc = f1 * f1 * ssa + 2.f * f1 * f2 * ssab + f2 * f2 * ssb;
        f3 = NS_F * sqrtf(DS_F / (ssc + 1e-5f));
    }
#pragma unroll
    for (int j = 0; j < 4; ++j) {
        const int s = s0 + ty + j * 8;
        const int d = d0 + tx;
        const size_t o = ((size_t)b * SEQ + s) * DM + d;
        const size_t xo = ((size_t)b * SEQ + s) * 1024 + d;
        float v;
        if (mode == 0) v = f3 * Tin[o];
        else {
            const float x = bf2f(XCin[xo]) + bf2f(XCin[xo + 512]);
            v = f3 * (f1 * x * mv[(size_t)b * SEQ + s] + f2 * Tin[o]);
        }
        if (writeXC) {
            const us h = f2bf(v);
            XCout[xo] = h;
            XCout[xo + 512] = f2bf(v - bf2f(h));
        }
        tile[ty + j * 8][tx] = v;
    }
    __syncthreads();
#pragma unroll
    for (int j = 0; j < 4; ++j) {
        const int d = d0 + ty + j * 8;
        const int s = s0 + tx;
        const float v = tile[tx][ty + j * 8];
        const size_t o = ((size_t)b * DM + d) * SEQ + s;
        if (XTb) XTb[o] = f2bf(v);
        else if (XTf) XTf[o] = v;
    }
}

extern "C" void kernel_launch(void* const* d_in, const int* in_sizes, int n_in,
                              void* d_out, int out_size, void* d_ws, size_t ws_size,
                              hipStream_t stream) {
    const float* train_feat = (const float*)d_in[0];
    const float* test_feat  = (const float*)d_in[1];
    const float* label      = (const float*)d_in[2];
    const float* WKs        = (const float*)d_in[3];
    const float* bKs        = (const float*)d_in[4];
    const float* WKc        = (const float*)d_in[5];
    const float* bKc        = (const float*)d_in[6];
    float* out = (float*)d_out;
    float* w = (float*)d_ws;

    const size_t PB  = (size_t)SEQ * DM;        // 524,288 elems per batch
    const size_t SBD = (size_t)NB * PB;         // 16-batch slab

    // choose merged (32-batch stream) if workspace allows
    auto needF = [&](size_t nbat) {
        return nbat * (PB /*T*/ + PB /*XC(us2)*/ + PB / 2 /*XTd*/ + PB / 4 /*W1C*/ + 1024 /*MVEC*/)
             + (size_t)NB * (PB / 2 /*MEMT*/ + PB / 2 /*MEMLT*/ + PB / 4 /*WKMC*/)
             + 2 * (size_t)KD * 512 /*WCs+WCc*/ + SS_FLOATS + 4096;
    };
    const size_t wsf = ws_size / 4;
    const int nbat = (wsf >= needF(32)) ? 32 : NB;

    float* T    = w;                                   // nbat*PB f32
    us* XC      = (us*)(T + (size_t)nbat * PB);        // nbat*2*PB us (hi|lo)
    us* XTd     = XC + (size_t)nbat * 2 * PB;          // nbat*PB us
    us* W1C     = XTd + (size_t)nbat * PB;             // nbat*PB/2 us
    us* MEMT    = W1C + (size_t)nbat * PB / 2;         // NB*PB us
    us* MEMLT   = MEMT + (size_t)NB * PB;              // NB*PB us
    us* WKMC    = MEMLT + (size_t)NB * PB;             // NB*PB/2 us
    us* WCs     = WKMC + (size_t)NB * PB / 2;          // KD*1024 us
    us* WCc     = WCs + (size_t)KD * 1024;
    float* MVEC = (float*)(WCc + (size_t)KD * 1024);   // nbat*SEQ f32
    float* SS   = MVEC + (size_t)nbat * SEQ;           // SS_FLOATS

    const dim3 gT_in(DM / 32, SEQ / 32, NB), bT(32, 8);

    int stage = 0;
    auto nextSS = [&]() { return SS + (size_t)(stage++) * SS_STRIDE; };

    // ---------------- setup ----------------
    k_zero<<<(SS_FLOATS + 255) / 256, 256, 0, stream>>>(SS);
    k_wsplit<<<KD, 256, 0, stream>>>(WKs, WCs);
    k_wsplit<<<KD, 256, 0, stream>>>(WKc, WCc);

    // ---------------- encoder (16 batches, in first 16 slots) ----------------
    k_transpose_in<<<gT_in, bT, 0, stream>>>(train_feat, XC, MEMT);
    for (int l = 0; l < 2; ++l) {
        float* SSst = nextSS();
        k_proj<<<NB * SEQ / 32, 256, 0, stream>>>(XC, WCs, bKs, W1C);
        k_attn<<<dim3(NB, SEQ / 64), 512, 0, stream>>>(W1C, W1C, MEMT, XC, nullptr, nullptr, T, SSst, 1, 63);
        k_finish<<<dim3(SEQ / 32, DM / 32, NB), bT, 0, stream>>>(T, XC, nullptr, SSst, XC, MEMT, nullptr, 0, 1);
    }
    k_proj<<<NB * SEQ / 32, 256, 0, stream>>>(XC, WCc, bKc, WKMC);
    k_mklabel<<<dim3(DM * SEQ / 8 / 256, NB), 256, 0, stream>>>(MEMT, label, MEMLT);

    // ---------------- decoder stages over `db` batches starting at slot 0 ----------------
    auto dec_layers = [&](int db, float* outp) {
        const dim3 gA(db, SEQ / 64);
        const dim3 gF(SEQ / 32, DM / 32, db);
        for (int l = 0; l < 2; ++l) {
            // self-attn + inorm
            float* SSst = nextSS();
            k_proj<<<db * SEQ / 32, 256, 0, stream>>>(XC, WCs, bKs, W1C);
            k_attn<<<gA, 512, 0, stream>>>(W1C, W1C, XTd, XC, nullptr, nullptr, T, SSst, 1, 63);
            k_finish<<<gF, bT, 0, stream>>>(T, XC, nullptr, SSst, XC, XTd, nullptr, 0, 1);
            // cross-attn (fused reduce3): T = x + t3; SS = ssa/ssb/ssab; MVEC = mask
            float* SSst2 = nextSS();
            k_proj<<<db * SEQ / 32, 256, 0, stream>>>(XC, WCc, bKc, W1C);
            k_attn<<<gA, 512, 0, stream>>>(W1C, WKMC, MEMLT, XC, label, MVEC, T, SSst2, 2, 15);
            // fused triple instance-norm finish
            if (l == 0)
                k_finish<<<gF, bT, 0, stream>>>(T, XC, MVEC, SSst2, XC, XTd, nullptr, 1, 1);
            else
                k_finish<<<gF, bT, 0, stream>>>(T, XC, MVEC, SSst2, XC, nullptr, outp, 1, 0);
        }
    };

    if (nbat == 32) {
        // merged: train -> slots 0..15, test -> slots 16..31; out is contiguous [32][D][S]
        k_transpose_in<<<gT_in, bT, 0, stream>>>(train_feat, XC, XTd);
        k_transpose_in<<<gT_in, bT, 0, stream>>>(test_feat, XC + (size_t)NB * 2 * PB, XTd + (size_t)NB * PB);
        dec_layers(32, out);
    } else {
        k_transpose_in<<<gT_in, bT, 0, stream>>>(train_feat, XC, XTd);
        dec_layers(NB, out);
        k_transpose_in<<<gT_in, bT, 0, stream>>>(test_feat, XC, XTd);
        dec_layers(NB, out + SBD);
    }
}